// Round 19
// baseline (130.201 us; speedup 1.0000x reference)
//
#include <hip/hip_runtime.h>
#include <hip/hip_bf16.h>

// DeformableConvBlock: B=8, C=64, H=W=128
#define BB 8
#define CC 64
#define C2 128
#define HH 128
#define WW 128
#define HW (HH * WW)

typedef __attribute__((ext_vector_type(8))) short bf16x8;
typedef __attribute__((ext_vector_type(4))) float f32x4;
typedef __attribute__((ext_vector_type(16))) float f32x16;
typedef __attribute__((ext_vector_type(2))) float f32x2;
typedef __attribute__((ext_vector_type(4))) unsigned u32x4;

__device__ inline ushort f2bf(float f) {
    union { float f; unsigned u; } v; v.f = f;
    unsigned r = v.u + 0x7fff + ((v.u >> 16) & 1);   // RNE
    return (ushort)(r >> 16);
}
__device__ inline float bf2f(ushort u) {
    union { unsigned u; float f; } v; v.u = (unsigned)u << 16; return v.f;
}

// ---------------------------------------------------------------------------
// Pre-pass: concat(lr,hr) fp32 NCHW -> bf16 NHWC [b][y][x][128ci]
// ---------------------------------------------------------------------------
__global__ __launch_bounds__(256) void to_nhwc_bf16(
    const float* __restrict__ lr, const float* __restrict__ hr,
    ushort* __restrict__ dst) {
    __shared__ ushort lt[HH][136];
    const int t = threadIdx.x;
    const int b = blockIdx.x >> 7, y = blockIdx.x & 127;
    for (int ci0 = 0; ci0 < 128; ci0 += 2) {
        const int ci = ci0 + (t >> 7);
        const int x = t & 127;
        const float* s = (ci < 64) ? lr + ((size_t)(b * 64 + ci)) * HW
                                   : hr + ((size_t)(b * 64 + ci - 64)) * HW;
        lt[x][ci] = f2bf(s[y * WW + x]);
    }
    __syncthreads();
    ushort* db = dst + ((size_t)blockIdx.x) * WW * 128;
    for (int i = t; i < 128 * 16; i += 256) {
        const int px = i >> 4, q = i & 15;
        uint4 v = *(const uint4*)&lt[px][q * 8];
        *(uint4*)&db[(size_t)px * 128 + q * 8] = v;
    }
}

// ---------------------------------------------------------------------------
// Fused weight packs + zp zeroing (one launch).
// wE2: [kb][128co][8], kb=(cc*9+tap)*4+lg, ci=cc*32+lg*8+c7   (147,456)
// wO2: [kb][32co][8], co>=18 zero-padded                       (36,864)
// wD4: [tap][h][lg][64co][8], c=h*32+lg*8+c7                   (36,864)
// ---------------------------------------------------------------------------
__global__ void pack_all(const float* __restrict__ wE, const float* __restrict__ wO,
                         const float* __restrict__ wD, ushort* __restrict__ oE,
                         ushort* __restrict__ oO, ushort* __restrict__ oD,
                         ushort* __restrict__ zp) {
    int i = blockIdx.x * 256 + threadIdx.x;
    if (i < 147456) {
        int c7 = i & 7, co = (i >> 3) & 127, kb = i >> 10;
        int lg = kb & 3, ct = kb >> 2, tap = ct % 9, cc = ct / 9;
        int ci = cc * 32 + lg * 8 + c7;
        oE[i] = f2bf(wE[((size_t)co * 128 + ci) * 9 + tap]);
        return;
    }
    i -= 147456;
    if (i < 36864) {
        int c7 = i & 7, co = (i >> 3) & 31, kb = i >> 8;
        int lg = kb & 3, ct = kb >> 2, tap = ct % 9, cc = ct / 9;
        int ci = cc * 32 + lg * 8 + c7;
        oO[i] = (co < 18) ? f2bf(wO[((size_t)co * 128 + ci) * 9 + tap]) : (ushort)0;
        return;
    }
    i -= 36864;
    if (i < 36864) {
        int c7 = i & 7, co = (i >> 3) & 63, lg = (i >> 9) & 3, h = (i >> 11) & 1,
            tap = i >> 12;
        int c = h * 32 + lg * 8 + c7;
        oD[i] = f2bf(wD[((size_t)co * 64 + c) * 9 + tap]);
        return;
    }
    i -= 36864;
    if (i < 128) zp[i] = 0;
}

// ---------------------------------------------------------------------------
// conv1 v9: CO-SPLIT for residency.  Grid 512 blocks = (b, 4-row tile,
// co-half); 8 waves = 4 rows x 2 px-halves; wave tile 64px x 64co
// (acc f32x16[2][2] = 64 VGPR).  Same 50KB A-staging per block (both
// co-halves stage identical rows: FETCH 2x, L2-hit via XCD swizzle).
// 2 blocks/CU = 4 waves/SIMD -> cross-block latency hiding (m114).
// 32x32x16 MFMA (r18: conflict-free, denser pipe).
// ---------------------------------------------------------------------------
#define SLOTS 3120         // 6*4*130
#define SLOTS_PAD 3136

__global__ __launch_bounds__(512) void conv1_mfma(
    const ushort* __restrict__ nhwc, const ushort* __restrict__ wE2,
    const ushort* __restrict__ zp, ushort* __restrict__ est) {
    __shared__ ushort lws[SLOTS_PAD * 8];      // 50,176 B
    const int t = threadIdx.x, lane = t & 63, wid = t >> 6;
    const int l31 = lane & 31, l32h = lane >> 5;
    const int wm = wid >> 1, wn = wid & 1;     // row-in-tile (0..3), px-half
    const int bi0 = blockIdx.x;
    const int bi = (bi0 & 7) * 64 + (bi0 >> 3);      // XCD swizzle (512 wg)
    const int b = bi >> 6;
    const int yt = (bi & 63) >> 1;
    const int coh = bi & 1;                    // co half: [coh*64, coh*64+64)
    const int y0 = yt * 4;
    const ushort* nb = nhwc + (size_t)(b * HH) * WW * 128;

    auto stage = [&](int cc) {
        for (int s0 = wid * 64; s0 < SLOTS; s0 += 512) {
            const int s = s0 + lane;
            const int sc = (s < SLOTS) ? s : (SLOTS - 1);
            const int plane = sc / 130, px = sc % 130;
            const int r = plane >> 2, q = plane & 3;
            const int yy = y0 + r - 1, xx = px - 1;
            const ushort* g =
                ((unsigned)yy < (unsigned)HH && (unsigned)xx < (unsigned)WW)
                    ? nb + ((size_t)yy * WW + xx) * 128 + cc * 32 + q * 8
                    : zp;
            __builtin_amdgcn_global_load_lds(
                (const __attribute__((address_space(1))) void*)g,
                (__attribute__((address_space(3))) void*)(&lws[s0 * 8]),
                16, 0, 0);
        }
    };

    f32x16 acc[2][2] = {};
#pragma unroll
    for (int cc = 0; cc < 4; ++cc) {
        stage(cc);
        __syncthreads();               // stage(cc) resident
#pragma unroll
        for (int tap = 0; tap < 9; ++tap) {
            const int ky = tap / 3, kx = tap % 3;
            bf16x8 a[2][2], w[2][2];
#pragma unroll
            for (int pt = 0; pt < 2; ++pt)
#pragma unroll
                for (int ks = 0; ks < 2; ++ks) {
                    const int plane = (wm + ky) * 4 + ks * 2 + l32h;
                    const int px = wn * 64 + pt * 32 + l31 + kx;
                    a[pt][ks] = *(const bf16x8*)&lws[(plane * 130 + px) * 8];
                }
#pragma unroll
            for (int ct = 0; ct < 2; ++ct)
#pragma unroll
                for (int ks = 0; ks < 2; ++ks)
                    w[ct][ks] = *(const bf16x8*)
                        &wE2[(size_t)(((cc * 9 + tap) * 4 + ks * 2 + l32h) * 128
                                      + coh * 64 + ct * 32 + l31) * 8];
#pragma unroll
            for (int pt = 0; pt < 2; ++pt)
#pragma unroll
                for (int ct = 0; ct < 2; ++ct)
#pragma unroll
                    for (int ks = 0; ks < 2; ++ks)
                        acc[pt][ct] = __builtin_amdgcn_mfma_f32_32x32x16_bf16(
                            a[pt][ks], w[ct][ks], acc[pt][ct], 0, 0, 0);
        }
        __syncthreads();               // all waves done reading before re-stage
    }

    const int y = y0 + wm;
    ushort* eb = est + ((size_t)(b * HH + y)) * WW * 128;
#pragma unroll
    for (int pt = 0; pt < 2; ++pt)
#pragma unroll
        for (int ct = 0; ct < 2; ++ct)
#pragma unroll
            for (int j = 0; j < 16; ++j) {
                float r = acc[pt][ct][j];
                r = (r >= 0.f) ? r : 0.1f * r;
                const int px = wn * 64 + pt * 32 + (j & 3) + 8 * (j >> 2) + 4 * l32h;
                const int co = coh * 64 + ct * 32 + l31;
                eb[(size_t)px * 128 + co] = f2bf(r);
            }
}

// ---------------------------------------------------------------------------
// conv2 v7 (unchanged from r17): single-buffer 2-barrier, 16x16 MFMA.
// A = weights (32 co, 18 valid), B = est pixels; XCD swizzle.
// ---------------------------------------------------------------------------
__global__ __launch_bounds__(512) void conv2_mfma(
    const ushort* __restrict__ est, const ushort* __restrict__ wO2,
    const ushort* __restrict__ zp, float* __restrict__ offs) {
    __shared__ ushort lws[SLOTS_PAD * 8];
    const int t = threadIdx.x, lane = t & 63, wid = t >> 6;
    const int l15 = lane & 15, lg = lane >> 4;
    const int wm = wid >> 1, wn = wid & 1;
    const int bi0 = blockIdx.x;
    const int bi = (bi0 & 7) * 32 + (bi0 >> 3);      // XCD swizzle (256 wg)
    const int b = bi >> 5, yt = bi & 31;
    const int y0 = yt * 4;
    const ushort* nb = est + (size_t)(b * HH) * WW * 128;

    auto stage = [&](int cc) {
        for (int s0 = wid * 64; s0 < SLOTS; s0 += 512) {
            const int s = s0 + lane;
            const int sc = (s < SLOTS) ? s : (SLOTS - 1);
            const int plane = sc / 130, px = sc % 130;
            const int r = plane >> 2, q = plane & 3;
            const int yy = y0 + r - 1, xx = px - 1;
            const ushort* g =
                ((unsigned)yy < (unsigned)HH && (unsigned)xx < (unsigned)WW)
                    ? nb + ((size_t)yy * WW + xx) * 128 + cc * 32 + q * 8
                    : zp;
            __builtin_amdgcn_global_load_lds(
                (const __attribute__((address_space(1))) void*)g,
                (__attribute__((address_space(3))) void*)(&lws[s0 * 8]),
                16, 0, 0);
        }
    };

    f32x4 acc[2][4] = {};
#pragma unroll
    for (int cc = 0; cc < 4; ++cc) {
        stage(cc);
        __syncthreads();
#pragma unroll
        for (int tap = 0; tap < 9; ++tap) {
            const int ky = tap / 3, kx = tap % 3;
            bf16x8 aw[2], bx[4];
#pragma unroll
            for (int mt = 0; mt < 2; ++mt)
                aw[mt] = *(const bf16x8*)&wO2[(size_t)(((cc * 9 + tap) * 4 + lg) * 32
                                                      + mt * 16 + l15) * 8];
#pragma unroll
            for (int nt = 0; nt < 4; ++nt)
                bx[nt] = *(const bf16x8*)
                    &lws[(((wm + ky) * 4 + lg) * 130
                          + wn * 64 + nt * 16 + l15 + kx) * 8];
#pragma unroll
            for (int mt = 0; mt < 2; ++mt)
#pragma unroll
                for (int nt = 0; nt < 4; ++nt)
                    acc[mt][nt] = __builtin_amdgcn_mfma_f32_16x16x32_bf16(
                        aw[mt], bx[nt], acc[mt][nt], 0, 0, 0);
        }
        __syncthreads();
    }

    const int y = y0 + wm;
    float* obp = offs + (size_t)b * 18 * HW + (size_t)y * WW;
#pragma unroll
    for (int mt = 0; mt < 2; ++mt)
#pragma unroll
        for (int j = 0; j < 4; ++j) {
            const int co = mt * 16 + lg * 4 + j;
            if (co < 18)
#pragma unroll
                for (int nt = 0; nt < 4; ++nt)
                    obp[(size_t)co * HW + wn * 64 + nt * 16 + l15] = acc[mt][nt][j];
        }
}

// ---------------------------------------------------------------------------
// Deformable conv v9 (r12/r14-proven): pixel-major gather mapping (adjacent-
// lane line-merge), asm-pinned full-drain pipeline, all-taps weights in LDS,
// shfl re-layout, XCD swizzle.
// ---------------------------------------------------------------------------
__device__ inline void def_coords(const ushort* __restrict__ nb, int y, int x,
                                  int k, float dy, float dx, int chan_base,
                                  float* __restrict__ w,
                                  const ushort** __restrict__ p) {
    const int ky = k / 3 - 1, kx = k % 3 - 1;
    const float py  = (float)(y + ky) + dy;
    const float pxf = (float)(x + kx) + dx;
    const float y0f = floorf(py), x0f = floorf(pxf);
    const float wy1 = py - y0f, wx1 = pxf - x0f;
    const float wy0 = 1.f - wy1, wx0 = 1.f - wx1;
    const int y0 = (int)y0f, x0 = (int)x0f;
    const int y1 = y0 + 1, x1 = x0 + 1;
    const bool vy0 = (unsigned)y0 < (unsigned)HH;
    const bool vy1 = (unsigned)y1 < (unsigned)HH;
    const bool vx0 = (unsigned)x0 < (unsigned)WW;
    const bool vx1 = (unsigned)x1 < (unsigned)WW;
    w[0] = wy0 * wx0 * ((vy0 && vx0) ? 1.f : 0.f);
    w[1] = wy0 * wx1 * ((vy0 && vx1) ? 1.f : 0.f);
    w[2] = wy1 * wx0 * ((vy1 && vx0) ? 1.f : 0.f);
    w[3] = wy1 * wx1 * ((vy1 && vx1) ? 1.f : 0.f);
    const int y0c = min(max(y0, 0), HH - 1), y1c = min(max(y1, 0), HH - 1);
    const int x0c = min(max(x0, 0), WW - 1), x1c = min(max(x1, 0), WW - 1);
    p[0] = nb + ((size_t)y0c * WW + x0c) * 128 + chan_base;
    p[1] = nb + ((size_t)y0c * WW + x1c) * 128 + chan_base;
    p[2] = nb + ((size_t)y1c * WW + x0c) * 128 + chan_base;
    p[3] = nb + ((size_t)y1c * WW + x1c) * 128 + chan_base;
}

__global__ __launch_bounds__(512) void deform_mfma(
    const ushort* __restrict__ nhwc,   // [b][y][x][128]
    const float* __restrict__ offs,    // [b][18][H][W]
    const ushort* __restrict__ wD4,    // [9][2][4][64][8]
    float* __restrict__ out) {         // [b][64][H][W]
    __shared__ ushort wlds[9 * 4096];  // 72 KB: ALL taps' weights
    const int t = threadIdx.x, lane = t & 63, wid = t >> 6;
    const int l15 = lane & 15, lg = lane >> 4;
    const int pg = lane >> 2, q = lane & 3;      // load-phase mapping
    const int bi0 = blockIdx.x;
    const int bi = (bi0 & 7) * 128 + (bi0 >> 3); // XCD swizzle (1024 wg)
    const int xh = bi & 1, yp = (bi >> 1) & 63, b = bi >> 7;
    const int y  = yp * 2 + (wid >> 2);
    const int xo = xh * 64 + (wid & 3) * 16 + l15;   // output pixel (MFMA col)
    const int xl = xh * 64 + (wid & 3) * 16 + pg;    // load-phase pixel

    const ushort* nb = nhwc + (size_t)(b * HH) * WW * 128;
    const float* obl = offs + (size_t)b * 18 * HW + (size_t)y * WW + xl;
    const int cbl = 64 + q * 8;
    const int shfl_src = (l15 << 2) | lg;

#pragma unroll
    for (int i = 0; i < 9; ++i) {
        const ushort* src = wD4 + i * 4096 + (wid * 64 + lane) * 8;
        __builtin_amdgcn_global_load_lds(
            (const __attribute__((address_space(1))) void*)src,
            (__attribute__((address_space(3))) void*)(&wlds[i * 4096 + wid * 512]),
            16, 0, 0);
    }

    float dyv[9], dxv[9];
#pragma unroll
    for (int k = 0; k < 9; ++k) {
        dyv[k] = obl[(size_t)(2 * k) * HW];
        dxv[k] = obl[(size_t)(2 * k + 1) * HW];
    }
    __syncthreads();

    auto issue_g = [&](int k, u32x4* g, float* wz) {
        const ushort* p[4];
        def_coords(nb, y, xl, k, dyv[k], dxv[k], cbl, wz, p);
#pragma unroll
        for (int c = 0; c < 4; ++c) {
            asm volatile("global_load_dwordx4 %0, %1, off"
                         : "=v"(g[c]) : "v"(p[c]));
            asm volatile("global_load_dwordx4 %0, %1, off offset:64"
                         : "=v"(g[4 + c]) : "v"(p[c]));
        }
    };

    u32x4 gcur[8], gnxt[8];
    float wcur[4], wnxt[4];
    issue_g(0, gcur, wcur);

    f32x4 acc[4] = {};
#pragma unroll
    for (int k = 0; k < 9; ++k) {
        asm volatile("s_waitcnt vmcnt(0)" ::: "memory");
        __builtin_amdgcn_sched_barrier(0);
        if (k < 8) issue_g(k + 1, gnxt, wnxt);
#pragma unroll
        for (int h = 0; h < 2; ++h) {
            bf16x8 afr[4];
#pragma unroll
            for (int mt = 0; mt < 4; ++mt)
                afr[mt] = *(const bf16x8*)
                    &wlds[(size_t)(((k * 2 + h) * 4 + lg) * 64 + mt * 16 + l15) * 8];
            union { unsigned u[4]; bf16x8 v; } bv;
#pragma unroll
            for (int qq = 0; qq < 4; ++qq) {
                f32x2 s = {0.f, 0.f};
#pragma unroll
                for (int c = 0; c < 4; ++c) {
                    const unsigned u = gcur[h * 4 + c][qq];
                    f32x2 cf;
                    cf.x = __uint_as_float(u << 16);
                    cf.y = __uint_as_float(u & 0xffff0000u);
                    s.x = fmaf(wcur[c], cf.x, s.x);
                    s.y = fmaf(wcur[c], cf.y, s.y);
                }
                __hip_bfloat162 hh = __float22bfloat162_rn(make_float2(s.x, s.y));
                unsigned up; __builtin_memcpy(&up, &hh, 4);
                bv.u[qq] = (unsigned)__shfl((int)up, shfl_src);
            }
#pragma unroll
            for (int mt = 0; mt < 4; ++mt)
                acc[mt] = __builtin_amdgcn_mfma_f32_16x16x32_bf16(
                    afr[mt], bv.v, acc[mt], 0, 0, 0);
        }
#pragma unroll
        for (int c = 0; c < 8; ++c) gcur[c] = gnxt[c];
#pragma unroll
        for (int c = 0; c < 4; ++c) wcur[c] = wnxt[c];
    }

#pragma unroll
    for (int mt = 0; mt < 4; ++mt)
#pragma unroll
        for (int j = 0; j < 4; ++j) {
            const int co = mt * 16 + lg * 4 + j;
            out[(((size_t)(b * CC + co)) * HH + y) * WW + xo] = acc[mt][j];
        }
}

// ---------------------------------------------------------------------------
// Workspace:
//   in_nhwc  bf16  33,554,432
//   est_nhwc bf16  33,554,432
//   offs     f32    9,437,184
//   wE2      bf16     294,912
//   wO2      bf16      73,728
//   wD4      bf16      73,728
//   zpage             256 (zeroed by pack_all)
// total ~77 MB
// ---------------------------------------------------------------------------
extern "C" void kernel_launch(void* const* d_in, const int* in_sizes, int n_in,
                              void* d_out, int out_size, void* d_ws, size_t ws_size,
                              hipStream_t stream) {
    const float* lr    = (const float*)d_in[0];
    const float* hr    = (const float*)d_in[1];
    const float* w_est = (const float*)d_in[2];
    const float* w_off = (const float*)d_in[3];
    const float* w_def = (const float*)d_in[4];
    float* out = (float*)d_out;

    char* ws = (char*)d_ws;
    ushort* in_nhwc  = (ushort*)ws;   ws += (size_t)BB * HH * WW * 128 * 2;
    ushort* est_nhwc = (ushort*)ws;   ws += (size_t)BB * HH * WW * 128 * 2;
    float*  offs     = (float*)ws;    ws += (size_t)BB * 18 * HW * 4;
    ushort* wE2      = (ushort*)ws;   ws += (size_t)128 * 1152 * 2;
    ushort* wO2      = (ushort*)ws;   ws += (size_t)144 * 32 * 8 * 2;
    ushort* wD4      = (ushort*)ws;   ws += (size_t)9 * 4096 * 2;
    ushort* zp       = (ushort*)ws;

    const int pack_total = 147456 + 36864 + 36864 + 128;
    pack_all<<<(pack_total + 255) / 256, 256, 0, stream>>>(
        w_est, w_off, w_def, wE2, wO2, wD4, zp);

    to_nhwc_bf16<<<BB * HH, 256, 0, stream>>>(lr, hr, in_nhwc);

    conv1_mfma<<<BB * (HH / 4) * 2, 512, 0, stream>>>(in_nhwc, wE2, zp, est_nhwc);
    conv2_mfma<<<BB * (HH / 4), 512, 0, stream>>>(est_nhwc, wO2, zp, offs);

    deform_mfma<<<BB * HH, 512, 0, stream>>>(in_nhwc, offs, wD4, out);
}

// Round 20
// 120.700 us; speedup vs baseline: 1.0787x; 1.0787x over previous
//
#include <hip/hip_runtime.h>
#include <hip/hip_bf16.h>

// DeformableConvBlock: B=8, C=64, H=W=128
#define BB 8
#define CC 64
#define C2 128
#define HH 128
#define WW 128
#define HW (HH * WW)

typedef __attribute__((ext_vector_type(8))) short bf16x8;
typedef __attribute__((ext_vector_type(4))) float f32x4;
typedef __attribute__((ext_vector_type(16))) float f32x16;
typedef __attribute__((ext_vector_type(2))) float f32x2;
typedef __attribute__((ext_vector_type(4))) unsigned u32x4;

__device__ inline ushort f2bf(float f) {
    union { float f; unsigned u; } v; v.f = f;
    unsigned r = v.u + 0x7fff + ((v.u >> 16) & 1);   // RNE
    return (ushort)(r >> 16);
}
__device__ inline float bf2f(ushort u) {
    union { unsigned u; float f; } v; v.u = (unsigned)u << 16; return v.f;
}

// ---------------------------------------------------------------------------
// Pre-pass: concat(lr,hr) fp32 NCHW -> bf16 NHWC [b][y][x][128ci]
// ---------------------------------------------------------------------------
__global__ __launch_bounds__(256) void to_nhwc_bf16(
    const float* __restrict__ lr, const float* __restrict__ hr,
    ushort* __restrict__ dst) {
    __shared__ ushort lt[HH][136];
    const int t = threadIdx.x;
    const int b = blockIdx.x >> 7, y = blockIdx.x & 127;
    for (int ci0 = 0; ci0 < 128; ci0 += 2) {
        const int ci = ci0 + (t >> 7);
        const int x = t & 127;
        const float* s = (ci < 64) ? lr + ((size_t)(b * 64 + ci)) * HW
                                   : hr + ((size_t)(b * 64 + ci - 64)) * HW;
        lt[x][ci] = f2bf(s[y * WW + x]);
    }
    __syncthreads();
    ushort* db = dst + ((size_t)blockIdx.x) * WW * 128;
    for (int i = t; i < 128 * 16; i += 256) {
        const int px = i >> 4, q = i & 15;
        uint4 v = *(const uint4*)&lt[px][q * 8];
        *(uint4*)&db[(size_t)px * 128 + q * 8] = v;
    }
}

// ---------------------------------------------------------------------------
// Fused weight packs + zp zeroing (one launch).
// wE2: [kb][128co][8], kb=(cc*9+tap)*4+lg, ci=cc*32+lg*8+c7   (147,456)
// wO2: [kb][32co][8], co>=18 zero-padded                       (36,864)
// wD4: [tap][h][lg][64co][8], c=h*32+lg*8+c7                   (36,864)
// ---------------------------------------------------------------------------
__global__ void pack_all(const float* __restrict__ wE, const float* __restrict__ wO,
                         const float* __restrict__ wD, ushort* __restrict__ oE,
                         ushort* __restrict__ oO, ushort* __restrict__ oD,
                         ushort* __restrict__ zp) {
    int i = blockIdx.x * 256 + threadIdx.x;
    if (i < 147456) {
        int c7 = i & 7, co = (i >> 3) & 127, kb = i >> 10;
        int lg = kb & 3, ct = kb >> 2, tap = ct % 9, cc = ct / 9;
        int ci = cc * 32 + lg * 8 + c7;
        oE[i] = f2bf(wE[((size_t)co * 128 + ci) * 9 + tap]);
        return;
    }
    i -= 147456;
    if (i < 36864) {
        int c7 = i & 7, co = (i >> 3) & 31, kb = i >> 8;
        int lg = kb & 3, ct = kb >> 2, tap = ct % 9, cc = ct / 9;
        int ci = cc * 32 + lg * 8 + c7;
        oO[i] = (co < 18) ? f2bf(wO[((size_t)co * 128 + ci) * 9 + tap]) : (ushort)0;
        return;
    }
    i -= 36864;
    if (i < 36864) {
        int c7 = i & 7, co = (i >> 3) & 63, lg = (i >> 9) & 3, h = (i >> 11) & 1,
            tap = i >> 12;
        int c = h * 32 + lg * 8 + c7;
        oD[i] = f2bf(wD[((size_t)co * 64 + c) * 9 + tap]);
        return;
    }
    i -= 36864;
    if (i < 128) zp[i] = 0;
}

// ---------------------------------------------------------------------------
// conv1 v8 (r18-proven, 45.3 us): 32x32x16 MFMA, wave tile 128px x 64co,
// single-buffer 50KB LDS, 2-barrier loop, XCD swizzle, 256 blocks.
// ---------------------------------------------------------------------------
#define SLOTS 3120         // 6*4*130
#define SLOTS_PAD 3136

__global__ __launch_bounds__(512) void conv1_mfma(
    const ushort* __restrict__ nhwc, const ushort* __restrict__ wE2,
    const ushort* __restrict__ zp, ushort* __restrict__ est) {
    __shared__ ushort lws[SLOTS_PAD * 8];      // 50,176 B
    const int t = threadIdx.x, lane = t & 63, wid = t >> 6;
    const int l31 = lane & 31, l32h = lane >> 5;
    const int wm = wid >> 1, wn = wid & 1;     // row-in-tile, co-half
    const int bi0 = blockIdx.x;
    const int bi = (bi0 & 7) * 32 + (bi0 >> 3);      // XCD swizzle (256 wg)
    const int b = bi >> 5, yt = bi & 31;
    const int y0 = yt * 4;
    const ushort* nb = nhwc + (size_t)(b * HH) * WW * 128;

    auto stage = [&](int cc) {
        for (int s0 = wid * 64; s0 < SLOTS; s0 += 512) {
            const int s = s0 + lane;
            const int sc = (s < SLOTS) ? s : (SLOTS - 1);
            const int plane = sc / 130, px = sc % 130;
            const int r = plane >> 2, q = plane & 3;
            const int yy = y0 + r - 1, xx = px - 1;
            const ushort* g =
                ((unsigned)yy < (unsigned)HH && (unsigned)xx < (unsigned)WW)
                    ? nb + ((size_t)yy * WW + xx) * 128 + cc * 32 + q * 8
                    : zp;
            __builtin_amdgcn_global_load_lds(
                (const __attribute__((address_space(1))) void*)g,
                (__attribute__((address_space(3))) void*)(&lws[s0 * 8]),
                16, 0, 0);
        }
    };

    f32x16 acc[4][2] = {};
#pragma unroll
    for (int cc = 0; cc < 4; ++cc) {
        stage(cc);
        __syncthreads();               // stage(cc) resident
#pragma unroll
        for (int tap = 0; tap < 9; ++tap) {
            const int ky = tap / 3, kx = tap % 3;
            bf16x8 a[4][2], w[2][2];
#pragma unroll
            for (int pt = 0; pt < 4; ++pt)
#pragma unroll
                for (int ks = 0; ks < 2; ++ks) {
                    const int plane = (wm + ky) * 4 + ks * 2 + l32h;
                    const int px = pt * 32 + l31 + kx;
                    a[pt][ks] = *(const bf16x8*)&lws[(plane * 130 + px) * 8];
                }
#pragma unroll
            for (int ct = 0; ct < 2; ++ct)
#pragma unroll
                for (int ks = 0; ks < 2; ++ks)
                    w[ct][ks] = *(const bf16x8*)
                        &wE2[(size_t)(((cc * 9 + tap) * 4 + ks * 2 + l32h) * 128
                                      + wn * 64 + ct * 32 + l31) * 8];
#pragma unroll
            for (int pt = 0; pt < 4; ++pt)
#pragma unroll
                for (int ct = 0; ct < 2; ++ct)
#pragma unroll
                    for (int ks = 0; ks < 2; ++ks)
                        acc[pt][ct] = __builtin_amdgcn_mfma_f32_32x32x16_bf16(
                            a[pt][ks], w[ct][ks], acc[pt][ct], 0, 0, 0);
        }
        __syncthreads();               // all waves done reading before re-stage
    }

    const int y = y0 + wm;
    ushort* eb = est + ((size_t)(b * HH + y)) * WW * 128;
#pragma unroll
    for (int pt = 0; pt < 4; ++pt)
#pragma unroll
        for (int ct = 0; ct < 2; ++ct)
#pragma unroll
            for (int j = 0; j < 16; ++j) {
                float r = acc[pt][ct][j];
                r = (r >= 0.f) ? r : 0.1f * r;
                const int px = pt * 32 + (j & 3) + 8 * (j >> 2) + 4 * l32h;
                const int co = wn * 64 + ct * 32 + l31;
                eb[(size_t)px * 128 + co] = f2bf(r);
            }
}

// ---------------------------------------------------------------------------
// conv2 v7 (r17-proven): single-buffer 2-barrier, 16x16 MFMA.
// A = weights (32 co, 18 valid), B = est pixels; XCD swizzle.
// ---------------------------------------------------------------------------
__global__ __launch_bounds__(512) void conv2_mfma(
    const ushort* __restrict__ est, const ushort* __restrict__ wO2,
    const ushort* __restrict__ zp, float* __restrict__ offs) {
    __shared__ ushort lws[SLOTS_PAD * 8];
    const int t = threadIdx.x, lane = t & 63, wid = t >> 6;
    const int l15 = lane & 15, lg = lane >> 4;
    const int wm = wid >> 1, wn = wid & 1;
    const int bi0 = blockIdx.x;
    const int bi = (bi0 & 7) * 32 + (bi0 >> 3);      // XCD swizzle (256 wg)
    const int b = bi >> 5, yt = bi & 31;
    const int y0 = yt * 4;
    const ushort* nb = est + (size_t)(b * HH) * WW * 128;

    auto stage = [&](int cc) {
        for (int s0 = wid * 64; s0 < SLOTS; s0 += 512) {
            const int s = s0 + lane;
            const int sc = (s < SLOTS) ? s : (SLOTS - 1);
            const int plane = sc / 130, px = sc % 130;
            const int r = plane >> 2, q = plane & 3;
            const int yy = y0 + r - 1, xx = px - 1;
            const ushort* g =
                ((unsigned)yy < (unsigned)HH && (unsigned)xx < (unsigned)WW)
                    ? nb + ((size_t)yy * WW + xx) * 128 + cc * 32 + q * 8
                    : zp;
            __builtin_amdgcn_global_load_lds(
                (const __attribute__((address_space(1))) void*)g,
                (__attribute__((address_space(3))) void*)(&lws[s0 * 8]),
                16, 0, 0);
        }
    };

    f32x4 acc[2][4] = {};
#pragma unroll
    for (int cc = 0; cc < 4; ++cc) {
        stage(cc);
        __syncthreads();
#pragma unroll
        for (int tap = 0; tap < 9; ++tap) {
            const int ky = tap / 3, kx = tap % 3;
            bf16x8 aw[2], bx[4];
#pragma unroll
            for (int mt = 0; mt < 2; ++mt)
                aw[mt] = *(const bf16x8*)&wO2[(size_t)(((cc * 9 + tap) * 4 + lg) * 32
                                                      + mt * 16 + l15) * 8];
#pragma unroll
            for (int nt = 0; nt < 4; ++nt)
                bx[nt] = *(const bf16x8*)
                    &lws[(((wm + ky) * 4 + lg) * 130
                          + wn * 64 + nt * 16 + l15 + kx) * 8];
#pragma unroll
            for (int mt = 0; mt < 2; ++mt)
#pragma unroll
                for (int nt = 0; nt < 4; ++nt)
                    acc[mt][nt] = __builtin_amdgcn_mfma_f32_16x16x32_bf16(
                        aw[mt], bx[nt], acc[mt][nt], 0, 0, 0);
        }
        __syncthreads();
    }

    const int y = y0 + wm;
    float* obp = offs + (size_t)b * 18 * HW + (size_t)y * WW;
#pragma unroll
    for (int mt = 0; mt < 2; ++mt)
#pragma unroll
        for (int j = 0; j < 4; ++j) {
            const int co = mt * 16 + lg * 4 + j;
            if (co < 18)
#pragma unroll
                for (int nt = 0; nt < 4; ++nt)
                    obp[(size_t)co * HW + wn * 64 + nt * 16 + l15] = acc[mt][nt][j];
        }
}

// ---------------------------------------------------------------------------
// Deformable conv v10 = r18 structure + PACKED blend (f32x2 vector math ->
// v_pk_fma_f32, halves blend FMA issue; deform is VALU-bound at 58%).
// ---------------------------------------------------------------------------
__device__ inline void def_coords(const ushort* __restrict__ nb, int y, int x,
                                  int k, float dy, float dx, int chan_base,
                                  float* __restrict__ w,
                                  const ushort** __restrict__ p) {
    const int ky = k / 3 - 1, kx = k % 3 - 1;
    const float py  = (float)(y + ky) + dy;
    const float pxf = (float)(x + kx) + dx;
    const float y0f = floorf(py), x0f = floorf(pxf);
    const float wy1 = py - y0f, wx1 = pxf - x0f;
    const float wy0 = 1.f - wy1, wx0 = 1.f - wx1;
    const int y0 = (int)y0f, x0 = (int)x0f;
    const int y1 = y0 + 1, x1 = x0 + 1;
    const bool vy0 = (unsigned)y0 < (unsigned)HH;
    const bool vy1 = (unsigned)y1 < (unsigned)HH;
    const bool vx0 = (unsigned)x0 < (unsigned)WW;
    const bool vx1 = (unsigned)x1 < (unsigned)WW;
    w[0] = wy0 * wx0 * ((vy0 && vx0) ? 1.f : 0.f);
    w[1] = wy0 * wx1 * ((vy0 && vx1) ? 1.f : 0.f);
    w[2] = wy1 * wx0 * ((vy1 && vx0) ? 1.f : 0.f);
    w[3] = wy1 * wx1 * ((vy1 && vx1) ? 1.f : 0.f);
    const int y0c = min(max(y0, 0), HH - 1), y1c = min(max(y1, 0), HH - 1);
    const int x0c = min(max(x0, 0), WW - 1), x1c = min(max(x1, 0), WW - 1);
    p[0] = nb + ((size_t)y0c * WW + x0c) * 128 + chan_base;
    p[1] = nb + ((size_t)y0c * WW + x1c) * 128 + chan_base;
    p[2] = nb + ((size_t)y1c * WW + x0c) * 128 + chan_base;
    p[3] = nb + ((size_t)y1c * WW + x1c) * 128 + chan_base;
}

__global__ __launch_bounds__(512) void deform_mfma(
    const ushort* __restrict__ nhwc,   // [b][y][x][128]
    const float* __restrict__ offs,    // [b][18][H][W]
    const ushort* __restrict__ wD4,    // [9][2][4][64][8]
    float* __restrict__ out) {         // [b][64][H][W]
    __shared__ ushort wlds[9 * 4096];  // 72 KB: ALL taps' weights
    const int t = threadIdx.x, lane = t & 63, wid = t >> 6;
    const int l15 = lane & 15, lg = lane >> 4;
    const int pg = lane >> 2, q = lane & 3;      // load-phase mapping
    const int bi0 = blockIdx.x;
    const int bi = (bi0 & 7) * 128 + (bi0 >> 3); // XCD swizzle (1024 wg)
    const int xh = bi & 1, yp = (bi >> 1) & 63, b = bi >> 7;
    const int y  = yp * 2 + (wid >> 2);
    const int xo = xh * 64 + (wid & 3) * 16 + l15;   // output pixel (MFMA col)
    const int xl = xh * 64 + (wid & 3) * 16 + pg;    // load-phase pixel

    const ushort* nb = nhwc + (size_t)(b * HH) * WW * 128;
    const float* obl = offs + (size_t)b * 18 * HW + (size_t)y * WW + xl;
    const int cbl = 64 + q * 8;
    const int shfl_src = (l15 << 2) | lg;

#pragma unroll
    for (int i = 0; i < 9; ++i) {
        const ushort* src = wD4 + i * 4096 + (wid * 64 + lane) * 8;
        __builtin_amdgcn_global_load_lds(
            (const __attribute__((address_space(1))) void*)src,
            (__attribute__((address_space(3))) void*)(&wlds[i * 4096 + wid * 512]),
            16, 0, 0);
    }

    float dyv[9], dxv[9];
#pragma unroll
    for (int k = 0; k < 9; ++k) {
        dyv[k] = obl[(size_t)(2 * k) * HW];
        dxv[k] = obl[(size_t)(2 * k + 1) * HW];
    }
    __syncthreads();

    auto issue_g = [&](int k, u32x4* g, float* wz) {
        const ushort* p[4];
        def_coords(nb, y, xl, k, dyv[k], dxv[k], cbl, wz, p);
#pragma unroll
        for (int c = 0; c < 4; ++c) {
            asm volatile("global_load_dwordx4 %0, %1, off"
                         : "=v"(g[c]) : "v"(p[c]));
            asm volatile("global_load_dwordx4 %0, %1, off offset:64"
                         : "=v"(g[4 + c]) : "v"(p[c]));
        }
    };

    u32x4 gcur[8], gnxt[8];
    float wcur[4], wnxt[4];
    issue_g(0, gcur, wcur);

    f32x4 acc[4] = {};
#pragma unroll
    for (int k = 0; k < 9; ++k) {
        asm volatile("s_waitcnt vmcnt(0)" ::: "memory");
        __builtin_amdgcn_sched_barrier(0);
        if (k < 8) issue_g(k + 1, gnxt, wnxt);
#pragma unroll
        for (int h = 0; h < 2; ++h) {
            bf16x8 afr[4];
#pragma unroll
            for (int mt = 0; mt < 4; ++mt)
                afr[mt] = *(const bf16x8*)
                    &wlds[(size_t)(((k * 2 + h) * 4 + lg) * 64 + mt * 16 + l15) * 8];
            union { unsigned u[4]; bf16x8 v; } bv;
#pragma unroll
            for (int qq = 0; qq < 4; ++qq) {
                f32x2 s = {0.f, 0.f};
#pragma unroll
                for (int c = 0; c < 4; ++c) {
                    const unsigned u = gcur[h * 4 + c][qq];
                    f32x2 cf;
                    cf.x = __uint_as_float(u << 16);
                    cf.y = __uint_as_float(u & 0xffff0000u);
                    const f32x2 wv = {wcur[c], wcur[c]};
                    s = cf * wv + s;                   // v_pk_fma_f32
                }
                __hip_bfloat162 hh = __float22bfloat162_rn(make_float2(s.x, s.y));
                unsigned up; __builtin_memcpy(&up, &hh, 4);
                bv.u[qq] = (unsigned)__shfl((int)up, shfl_src);
            }
#pragma unroll
            for (int mt = 0; mt < 4; ++mt)
                acc[mt] = __builtin_amdgcn_mfma_f32_16x16x32_bf16(
                    afr[mt], bv.v, acc[mt], 0, 0, 0);
        }
#pragma unroll
        for (int c = 0; c < 8; ++c) gcur[c] = gnxt[c];
#pragma unroll
        for (int c = 0; c < 4; ++c) wcur[c] = wnxt[c];
    }

#pragma unroll
    for (int mt = 0; mt < 4; ++mt)
#pragma unroll
        for (int j = 0; j < 4; ++j) {
            const int co = mt * 16 + lg * 4 + j;
            out[(((size_t)(b * CC + co)) * HH + y) * WW + xo] = acc[mt][j];
        }
}

// ---------------------------------------------------------------------------
// Workspace:
//   in_nhwc  bf16  33,554,432
//   est_nhwc bf16  33,554,432
//   offs     f32    9,437,184
//   wE2      bf16     294,912
//   wO2      bf16      73,728
//   wD4      bf16      73,728
//   zpage             256 (zeroed by pack_all)
// total ~77 MB
// ---------------------------------------------------------------------------
extern "C" void kernel_launch(void* const* d_in, const int* in_sizes, int n_in,
                              void* d_out, int out_size, void* d_ws, size_t ws_size,
                              hipStream_t stream) {
    const float* lr    = (const float*)d_in[0];
    const float* hr    = (const float*)d_in[1];
    const float* w_est = (const float*)d_in[2];
    const float* w_off = (const float*)d_in[3];
    const float* w_def = (const float*)d_in[4];
    float* out = (float*)d_out;

    char* ws = (char*)d_ws;
    ushort* in_nhwc  = (ushort*)ws;   ws += (size_t)BB * HH * WW * 128 * 2;
    ushort* est_nhwc = (ushort*)ws;   ws += (size_t)BB * HH * WW * 128 * 2;
    float*  offs     = (float*)ws;    ws += (size_t)BB * 18 * HW * 4;
    ushort* wE2      = (ushort*)ws;   ws += (size_t)128 * 1152 * 2;
    ushort* wO2      = (ushort*)ws;   ws += (size_t)144 * 32 * 8 * 2;
    ushort* wD4      = (ushort*)ws;   ws += (size_t)9 * 4096 * 2;
    ushort* zp       = (ushort*)ws;

    const int pack_total = 147456 + 36864 + 36864 + 128;
    pack_all<<<(pack_total + 255) / 256, 256, 0, stream>>>(
        w_est, w_off, w_def, wE2, wO2, wD4, zp);

    to_nhwc_bf16<<<BB * HH, 256, 0, stream>>>(lr, hr, in_nhwc);

    conv1_mfma<<<BB * (HH / 4), 512, 0, stream>>>(in_nhwc, wE2, zp, est_nhwc);
    conv2_mfma<<<BB * (HH / 4), 512, 0, stream>>>(est_nhwc, wO2, zp, offs);

    deform_mfma<<<BB * HH, 512, 0, stream>>>(in_nhwc, offs, wD4, out);
}